// Round 5
// baseline (233.763 us; speedup 1.0000x reference)
//
#include <hip/hip_runtime.h>
#include <math.h>

// 1D grayscale dilation (max-plus conv), K=11, halo=5, fp32.
// out[i] = max_j ( x[i-5+j] + h[j] ),  h[j] = -(j-5)^2 / (4*scale)
//
// R4 (LDS tile) 81.7us, R5 (shuffles) 80.5us, R6 (direct global) 81.6us:
//   three structures, identical time, all VGPR<=24. VGPR=24 proves the
//   register minimizer serialized the loads (R6 needs 40 VGPRs for its 10
//   in-flight float4s) -> wave MLP ~2 -> latency-bound at ~2.5 TB/s while
//   the pure-store fill kernel hits 6.6 TB/s on the same memory system.
// R7/R7b (asm vmcnt pipeline): GPU abort. Root cause: "=v" (not "=&v")
//   load outputs let regalloc overlap dest with the address pair; async
//   dest write clobbers the address for loads 2..5 -> memory fault.
// R8 (this): same MLP fix, zero-risk mechanics. Keep R6's verified C++
//   loads (compiler owns the waitcnt ledger -> cannot crash) and defeat
//   the register minimizer with an empty-asm PIN that reads+writes all 10
//   loaded float4s at one program point: all 10 loads must be issued and
//   simultaneously live before any fmax consumes them -> per-wave MLP 10.
//   Verification signal: VGPR_Count must jump 24 -> >=56.

typedef float f32x4 __attribute__((ext_vector_type(4)));

#define BLOCK   256
#define QPT     2                      // quads per thread per tile iteration
#define TILEQ   (BLOCK * QPT)          // 512 quads per tile
#define MAXGRID 2048                   // 8 blocks/CU, grid-stride the rest

// Force all 10 loaded values live at this point (defeats load serialization).
#define PIN10(a0,a1,a2,a3,a4,b0,b1,b2,b3,b4)                          \
    asm volatile("" : "+v"(a0), "+v"(a1), "+v"(a2), "+v"(a3), "+v"(a4), \
                      "+v"(b0), "+v"(b1), "+v"(b2), "+v"(b3), "+v"(b4))

__device__ __forceinline__ f32x4 dilate_quad(
    f32x4 a0, f32x4 a1, f32x4 a2, f32x4 a3, f32x4 a4,
    float hp1, float hp2, float hp3, float hp4, float hp5)
{
    // w[k] = x[4*q - 8 + k], k = 0..19
    float w[20];
    w[0]=a0.x;  w[1]=a0.y;  w[2]=a0.z;  w[3]=a0.w;
    w[4]=a1.x;  w[5]=a1.y;  w[6]=a1.z;  w[7]=a1.w;
    w[8]=a2.x;  w[9]=a2.y;  w[10]=a2.z; w[11]=a2.w;
    w[12]=a3.x; w[13]=a3.y; w[14]=a3.z; w[15]=a3.w;
    w[16]=a4.x; w[17]=a4.y; w[18]=a4.z; w[19]=a4.w;
    f32x4 o;
#pragma unroll
    for (int i = 0; i < 4; ++i) {      // static indices after unroll
        const int c = 8 + i;
        float m = w[c];                // hp[0] == 0
        m = fmaxf(m, hp1 + fmaxf(w[c-1], w[c+1]));
        m = fmaxf(m, hp2 + fmaxf(w[c-2], w[c+2]));
        m = fmaxf(m, hp3 + fmaxf(w[c-3], w[c+3]));
        m = fmaxf(m, hp4 + fmaxf(w[c-4], w[c+4]));
        m = fmaxf(m, hp5 + fmaxf(w[c-5], w[c+5]));
        o[i] = m;
    }
    return o;
}

__global__ __launch_bounds__(BLOCK) void dilate1d_kernel(
    const f32x4* __restrict__ x4,
    const float* __restrict__ scale_p,
    f32x4*       __restrict__ out4,
    int n4,        // number of float4 elements in x / out
    int ntiles)    // ceil(n4 / TILEQ)
{
    const float  NEG  = -INFINITY;
    const f32x4  NEG4 = {NEG, NEG, NEG, NEG};

    // structuring element: hp[d] = -d^2/(4s)
    const float r4s = 1.0f / (4.0f * scale_p[0]);
    const float hp1 = -1.0f  * r4s;
    const float hp2 = -4.0f  * r4s;
    const float hp3 = -9.0f  * r4s;
    const float hp4 = -16.0f * r4s;
    const float hp5 = -25.0f * r4s;

    for (int tile = blockIdx.x; tile < ntiles; tile += gridDim.x) {
        const int t0 = tile * TILEQ;
        const int q0 = t0 + threadIdx.x;         // first quad of this thread
        const int q1 = q0 + BLOCK;               // second quad

        f32x4 A0, A1, A2, A3, A4, B0, B1, B2, B3, B4;
        const bool interior = (t0 >= 2) && (t0 + TILEQ + 2 <= n4);
        if (interior) {
            const f32x4* pa = x4 + (q0 - 2);
            const f32x4* pb = x4 + (q1 - 2);
            A0 = pa[0]; A1 = pa[1]; A2 = pa[2]; A3 = pa[3]; A4 = pa[4];
            B0 = pb[0]; B1 = pb[1]; B2 = pb[2]; B3 = pb[3]; B4 = pb[4];
        } else {
            // only the first and last tiles take this path
            int ga = q0 - 2, gb = q1 - 2;
            A0 = (ga+0 >= 0 && ga+0 < n4) ? x4[ga+0] : NEG4;
            A1 = (ga+1 >= 0 && ga+1 < n4) ? x4[ga+1] : NEG4;
            A2 = (ga+2 >= 0 && ga+2 < n4) ? x4[ga+2] : NEG4;
            A3 = (ga+3 >= 0 && ga+3 < n4) ? x4[ga+3] : NEG4;
            A4 = (ga+4 >= 0 && ga+4 < n4) ? x4[ga+4] : NEG4;
            B0 = (gb+0 >= 0 && gb+0 < n4) ? x4[gb+0] : NEG4;
            B1 = (gb+1 >= 0 && gb+1 < n4) ? x4[gb+1] : NEG4;
            B2 = (gb+2 >= 0 && gb+2 < n4) ? x4[gb+2] : NEG4;
            B3 = (gb+3 >= 0 && gb+3 < n4) ? x4[gb+3] : NEG4;
            B4 = (gb+4 >= 0 && gb+4 < n4) ? x4[gb+4] : NEG4;
        }
        PIN10(A0, A1, A2, A3, A4, B0, B1, B2, B3, B4);

        f32x4 oa = dilate_quad(A0, A1, A2, A3, A4, hp1, hp2, hp3, hp4, hp5);
        f32x4 ob = dilate_quad(B0, B1, B2, B3, B4, hp1, hp2, hp3, hp4, hp5);
        if (q0 < n4) out4[q0] = oa;
        if (q1 < n4) out4[q1] = ob;
    }
}

extern "C" void kernel_launch(void* const* d_in, const int* in_sizes, int n_in,
                              void* d_out, int out_size, void* d_ws, size_t ws_size,
                              hipStream_t stream) {
    const float* x       = (const float*)d_in[0];
    const float* scale_p = (const float*)d_in[1];
    float*       out     = (float*)d_out;

    int n      = in_sizes[0];
    int n4     = n / 4;                          // n = 2^25 -> n4 = 2^23
    int ntiles = (n4 + TILEQ - 1) / TILEQ;       // 16384
    int grid   = ntiles < MAXGRID ? ntiles : MAXGRID;

    dilate1d_kernel<<<grid, BLOCK, 0, stream>>>(
        (const f32x4*)x, scale_p, (f32x4*)out, n4, ntiles);
}

// Round 6
// 229.387 us; speedup vs baseline: 1.0191x; 1.0191x over previous
//
#include <hip/hip_runtime.h>
#include <math.h>
#include <stdint.h>

// 1D grayscale dilation (max-plus conv), K=11, halo=5, fp32.
// out[i] = max_j ( x[i-5+j] + h[j] ),  h[j] = -(j-5)^2 / (4*scale)
//
// R4 (LDS tile) 81.7us, R5 (shuffles) 80.5us, R6 (direct global) 81.6us,
// R8 (pin-forced liveness) 79.4us: four structures, identical time.
//   Common factor: loaded data always lands in compiler-owned VGPR
//   destinations -> register minimizer serializes load->wait->consume
//   (VGPR stuck at 16-32 when 40+ needed) -> wave MLP ~1-2 -> latency-
//   bound at ~2.5 TB/s while pure-store fill hits 6.7 TB/s.
// R7/R7b (asm vmcnt pipeline): GPU abort ("=v" regalloc hazard).
// R9 (this): __builtin_amdgcn_global_load_lds staging -- the load has NO
//   VGPR destination, so there is nothing to serialize: each wave issues
//   its 4 staging loads back-to-back (MLP=4-5 x 1KiB by construction,
//   ~128KB outstanding per CU vs ~10KB Little's-law need). The
//   vmcnt(0)+barrier drain is the semantics we need, and 8 blocks/CU in
//   different phases overlap it. Compute phase identical to R4 (verified).
//   LDS layout stays linear/unpadded (global_load_lds requirement, m104).

typedef float f32x4 __attribute__((ext_vector_type(4)));

#define BLOCK   256
#define QPT     4                      // output quads per thread
#define TILE_Q  (BLOCK * QPT)          // 1024 quads per block
#define HALO_Q  2                      // staged halo quads each side
#define STAGE_Q (TILE_Q + 2 * HALO_Q)  // 1028 quads = 16448 B LDS

// Direct global->LDS 16B load. LDS dest = wave-uniform base + lane*16 (HW);
// global src is per-lane. AS casts via uintptr (CK pattern: LDS aperture is
// 4GiB-aligned, truncation of the flat addr yields the LDS offset).
__device__ __forceinline__ void gload_lds16(const f32x4* g, f32x4* l) {
    __builtin_amdgcn_global_load_lds(
        (const __attribute__((address_space(1))) uint32_t*)(uintptr_t)g,
        (__attribute__((address_space(3))) uint32_t*)(uintptr_t)l,
        16, 0, 0);
}

__global__ __launch_bounds__(BLOCK) void dilate1d_kernel(
    const f32x4* __restrict__ x4,
    const float* __restrict__ scale_p,
    f32x4*       __restrict__ out4,
    int n4)   // number of float4 elements in x / out
{
    __shared__ f32x4 smem[STAGE_Q];

    const float NEG  = -INFINITY;
    const f32x4 NEG4 = {NEG, NEG, NEG, NEG};

    const int Q0   = blockIdx.x * TILE_Q;        // first output quad of tile
    const int g0   = Q0 - HALO_Q;                // first staged quad (global)
    const int wid  = threadIdx.x >> 6;           // wave id (uniform per wave)

    // ---- stage tile + halo into LDS, direct-to-LDS (no VGPR round-trip) ----
    const bool interior = (g0 >= 0) && (g0 + STAGE_Q <= n4);
    if (interior) {
#pragma unroll
        for (int t = 0; t < QPT; ++t) {
            int idx = t * BLOCK + threadIdx.x;            // per-lane global
            gload_lds16(x4 + g0 + idx,                    // per-lane src
                        smem + t * BLOCK + wid * 64);     // wave-uniform dst
        }
        if (threadIdx.x < 2 * HALO_Q) {                   // lanes 0..3, wave 0
            gload_lds16(x4 + g0 + TILE_Q + threadIdx.x,
                        smem + TILE_Q);                   // wave-uniform dst
        }
    } else {
        // only blocks 0 and gridDim-1 take this path
#pragma unroll
        for (int t = 0; t <= QPT; ++t) {
            int idx = threadIdx.x + t * BLOCK;
            if (idx < STAGE_Q) {
                int g = g0 + idx;
                smem[idx] = (g >= 0 && g < n4) ? x4[g] : NEG4;
            }
        }
    }
    __syncthreads();   // drains vmcnt(0): LDS guaranteed filled

    // ---- structuring element: hp[d] = -d^2/(4s) ----
    const float r4s = 1.0f / (4.0f * scale_p[0]);
    const float hp1 = -1.0f  * r4s;
    const float hp2 = -4.0f  * r4s;
    const float hp3 = -9.0f  * r4s;
    const float hp4 = -16.0f * r4s;
    const float hp5 = -25.0f * r4s;

    // ---- compute: block-strided quads (lane-contiguous LDS reads/stores) ----
#pragma unroll
    for (int t = 0; t < QPT; ++t) {
        int idx = threadIdx.x + t * BLOCK;       // tile-local quad
        int q   = Q0 + idx;                      // global output quad
        if (q >= n4) break;

        // w[k] = x[4*q + k - 8], k = 0..19  (5 consecutive ds_read_b128)
        float w[20];
#pragma unroll
        for (int r = 0; r < 5; ++r) {
            f32x4 v = smem[idx + r];             // staged quad (idx+HALO_Q)-2+r
            w[4 * r + 0] = v.x;
            w[4 * r + 1] = v.y;
            w[4 * r + 2] = v.z;
            w[4 * r + 3] = v.w;
        }

        f32x4 o;
#pragma unroll
        for (int i = 0; i < 4; ++i) {
            int c = 8 + i;                       // center of window in w
            float m = w[c];                      // hp[0] == 0
            m = fmaxf(m, hp1 + fmaxf(w[c - 1], w[c + 1]));
            m = fmaxf(m, hp2 + fmaxf(w[c - 2], w[c + 2]));
            m = fmaxf(m, hp3 + fmaxf(w[c - 3], w[c + 3]));
            m = fmaxf(m, hp4 + fmaxf(w[c - 4], w[c + 4]));
            m = fmaxf(m, hp5 + fmaxf(w[c - 5], w[c + 5]));
            o[i] = m;
        }
        out4[q] = o;
    }
}

extern "C" void kernel_launch(void* const* d_in, const int* in_sizes, int n_in,
                              void* d_out, int out_size, void* d_ws, size_t ws_size,
                              hipStream_t stream) {
    const float* x       = (const float*)d_in[0];
    const float* scale_p = (const float*)d_in[1];
    float*       out     = (float*)d_out;

    int n  = in_sizes[0];
    int n4 = n / 4;                              // n = 2^25 -> n4 = 2^23

    int grid = (n4 + TILE_Q - 1) / TILE_Q;       // 8192 blocks

    dilate1d_kernel<<<grid, BLOCK, 0, stream>>>(
        (const f32x4*)x, scale_p, (f32x4*)out, n4);
}